// Round 10
// baseline (255.764 us; speedup 1.0000x reference)
//
#include <hip/hip_runtime.h>

typedef _Float16 hf8  __attribute__((ext_vector_type(8)));
typedef float  f32x16 __attribute__((ext_vector_type(16)));

constexpr int Bn = 512;
constexpr int Nn = 1024;
constexpr int Pn = 2016;
constexpr int H1c = 128;
constexpr int H2c = 64;
constexpr int NCc = 40;
constexpr int NT  = 640;    // threads per block (10 waves)
constexpr int NW  = 10;

// Pre-pack W2 (128x64 f32) + b2 into f16 A-fragments for mfma_f32_32x32x16_f16
// (R8-proven operand geometry), hi-only:
// idx = (((c*2+nt)*2 + kh)*32 + colm)*8 + jj ; c<8: W2[k= c*16+kh*8+jj][j= nt*32+colm]
// c==8: bias chunk — b2[j] in k-slot 0 (kh==0 && jj==0), zeros elsewhere.
__global__ void prep_w2(const float* __restrict__ W2, const float* __restrict__ b2,
                        _Float16* __restrict__ hi) {
    int i = blockIdx.x * 256 + threadIdx.x;
    if (i >= 9216) return;
    int jj = i & 7, colm = (i >> 3) & 31, kh = (i >> 8) & 1, nt = (i >> 9) & 1, c = i >> 10;
    int j = nt * 32 + colm;
    float v;
    if (c < 8) { int k = c * 16 + kh * 8 + jj; v = W2[k * H2c + j]; }
    else       { v = (kh == 0 && jj == 0) ? b2[j] : 0.f; }
    hi[i] = (_Float16)v;    // RNE, rel err <= 2^-11
}

__global__ __launch_bounds__(NT, 5)
void mlp_mfma(const float* __restrict__ x, const int* __restrict__ idx,
              const int* __restrict__ perms,
              const float* __restrict__ W1, const float* __restrict__ b1,
              const float* __restrict__ W3, const float* __restrict__ b3,
              const _Float16* __restrict__ w2hi,
              float* __restrict__ out)
{
    // fp16 pair-sum table: entry (gp = g*64 + k1*8+k2, h) at half-index
    //   gp*128 + ((hline ^ (gp&15))<<3) + (h&7),  hline = h>>3  (16B-line XOR swizzle)
    __shared__ _Float16 T2h[256 * 128];   // 64 KiB
    __shared__ float ptsl[24];
    __shared__ float wred[NW][64];
    __shared__ float Hs[64];

    const int t = threadIdx.x, b = blockIdx.x;

    if (t < 24) {
        int k = t / 3, c = t % 3;
        ptsl[t] = x[((size_t)b * Nn + idx[k]) * 3 + c];
    }
    __syncthreads();

    // ---- build T2: 32768 entries, b1 folded into g==0 ----
    #pragma unroll 1
    for (int i = 0; i < 52; ++i) {
        int e = t + i * NT;
        if (e < 32768) {
            int h = e & 127, gp = e >> 7;          // gp in 0..255
            int g = gp >> 6, p = gp & 63, k1 = p >> 3, k2 = p & 7;
            float v = ptsl[k1 * 3 + 0] * W1[(6 * g + 0) * H1c + h]
                    + ptsl[k1 * 3 + 1] * W1[(6 * g + 1) * H1c + h]
                    + ptsl[k1 * 3 + 2] * W1[(6 * g + 2) * H1c + h]
                    + ptsl[k2 * 3 + 0] * W1[(6 * g + 3) * H1c + h]
                    + ptsl[k2 * 3 + 1] * W1[(6 * g + 4) * H1c + h]
                    + ptsl[k2 * 3 + 2] * W1[(6 * g + 5) * H1c + h];
            if (g == 0) v += b1[h];
            T2h[(gp << 7) + (((h >> 3) ^ (gp & 15)) << 3) + (h & 7)] = (_Float16)v;
        }
    }
    __syncthreads();

    const int lane = t & 63, wave = t >> 6;
    const int kh = lane >> 5, colm = lane & 31;
    const char* Tb = (const char*)T2h;

    float vsum[32];
    #pragma unroll
    for (int q = 0; q < 32; ++q) vsum[q] = 0.f;

    // hoisted per-lane A base and bias fragments (loop-invariant).
    // bias chunk (c==8) starts at ELEMENT 8*1024 = 8192 (array is 9*1024 total):
    //   offset = (16+nt)*512 + kh*256 + colm*8  ->  w2L + 8192 (+512 for nt=1)
    const _Float16* w2L = w2hi + (kh * 32 + colm) * 8;      // + c*1024 (+512 for nt=1)
    const hf8 bias0 = *(const hf8*)(w2L + 8 * 1024);
    const hf8 bias1 = *(const hf8*)(w2L + 8 * 1024 + 512);
    hf8 Bone = {};
    if (kh == 0) Bone[0] = (_Float16)1.0f;

    // 63 tiles of 32 rows; wave w handles tiles w, w+10, ...
    #pragma unroll 1
    for (int tile = wave; tile < 63; tile += NW) {
        const int4* pp = (const int4*)(perms + ((size_t)b * Pn + (tile << 5) + colm) * 8);
        int4 pa = pp[0];
        int4 pb = pp[1];
        const int gp0 = pa.x * 8 + pa.y;
        const int gp1 = 64  + pa.z * 8 + pa.w;
        const int gp2 = 128 + pb.x * 8 + pb.y;
        const int gp3 = 192 + pb.z * 8 + pb.w;
        // per-row swizzled byte base: (gp<<8) | (((kh ^ (gp&1)) | (gp&14)) << 4)
        // per-chunk address = base ^ (c<<5)  (bit-exact vs ((2c+kh)^(gp&15))<<4)
        const int a0 = (gp0 << 8) | ((((kh ^ (gp0 & 1)) | (gp0 & 14))) << 4);
        const int a1 = (gp1 << 8) | ((((kh ^ (gp1 & 1)) | (gp1 & 14))) << 4);
        const int a2 = (gp2 << 8) | ((((kh ^ (gp2 & 1)) | (gp2 & 14))) << 4);
        const int a3 = (gp3 << 8) | ((((kh ^ (gp3 & 1)) | (gp3 & 14))) << 4);

        f32x16 acc0, acc1;
        #pragma unroll
        for (int q = 0; q < 16; ++q) { acc0[q] = 0.f; acc1[q] = 0.f; }

        #pragma unroll
        for (int c = 0; c < 8; ++c) {
            const int cx = c << 5;          // chunk XOR into bits 5-7 of byte addr
            hf8 r0 = *(const hf8*)(Tb + (a0 ^ cx));
            hf8 r1 = *(const hf8*)(Tb + (a1 ^ cx));
            hf8 r2 = *(const hf8*)(Tb + (a2 ^ cx));
            hf8 r3 = *(const hf8*)(Tb + (a3 ^ cx));
            hf8 s = (r0 + r1) + (r2 + r3);       // v_pk_add_f16
            hf8 z = {};
            s = __builtin_elementwise_max(s, z); // v_pk_max_f16 (relu) -> exact f16 B

            hf8 Ah0 = *(const hf8*)(w2L + c * 1024);
            hf8 Ah1 = *(const hf8*)(w2L + c * 1024 + 512);
            acc0 = __builtin_amdgcn_mfma_f32_32x32x16_f16(Ah0, s, acc0, 0, 0, 0);
            acc1 = __builtin_amdgcn_mfma_f32_32x32x16_f16(Ah1, s, acc1, 0, 0, 0);
        }

        // bias via one-hot MFMA (hoisted fragments)
        acc0 = __builtin_amdgcn_mfma_f32_32x32x16_f16(bias0, Bone, acc0, 0, 0, 0);
        acc1 = __builtin_amdgcn_mfma_f32_32x32x16_f16(bias1, Bone, acc1, 0, 0, 0);

        // relu + accumulate (layer-3 commutes with the mean over rows)
        #pragma unroll
        for (int r = 0; r < 16; ++r) vsum[r]      += fmaxf(acc0[r], 0.f);
        #pragma unroll
        for (int r = 0; r < 16; ++r) vsum[16 + r] += fmaxf(acc1[r], 0.f);
    }

    // ---- reduce over the 32 rows (lanes) per wave ----
    #pragma unroll
    for (int nt = 0; nt < 2; ++nt) {
        #pragma unroll
        for (int r = 0; r < 16; ++r) {
            int j = nt * 32 + (r & 3) + 8 * (r >> 2) + 4 * kh;   // verified C/D row mapping
            float v = vsum[nt * 16 + r];
            v += __shfl_xor(v, 1);
            v += __shfl_xor(v, 2);
            v += __shfl_xor(v, 4);
            v += __shfl_xor(v, 8);
            v += __shfl_xor(v, 16);
            if (colm == 0) wred[wave][j] = v;
        }
    }
    __syncthreads();

    if (t < 64) {
        float s2 = 0.f;
        #pragma unroll
        for (int w = 0; w < NW; ++w) s2 += wred[w][t];
        Hs[t] = s2;
    }
    __syncthreads();

    // ---- layer 3 once per block; block owns batch b -> direct store ----
    if (t < NCc) {
        constexpr float invP = 1.f / (float)Pn;
        float s3 = 0.f;
        #pragma unroll
        for (int j = 0; j < 64; ++j) s3 = fmaf(W3[j * NCc + t], Hs[j], s3);
        out[b * NCc + t] = b3[t] + s3 * invP;
    }
}

extern "C" void kernel_launch(void* const* d_in, const int* in_sizes, int n_in,
                              void* d_out, int out_size, void* d_ws, size_t ws_size,
                              hipStream_t stream) {
    const float* x     = (const float*)d_in[0];
    const int*   idx   = (const int*)  d_in[1];
    const int*   perms = (const int*)  d_in[2];
    const float* W1    = (const float*)d_in[3];
    const float* b1    = (const float*)d_in[4];
    const float* W2    = (const float*)d_in[5];
    const float* b2    = (const float*)d_in[6];
    const float* W3    = (const float*)d_in[7];
    const float* b3    = (const float*)d_in[8];
    float* out = (float*)d_out;

    _Float16* wsHi = (_Float16*)d_ws;

    hipLaunchKernelGGL(prep_w2, dim3(36), dim3(256), 0, stream, W2, b2, wsHi);
    hipLaunchKernelGGL(mlp_mfma, dim3(Bn), dim3(NT), 0, stream,
                       x, idx, perms, W1, b1, W3, b3, wsHi, out);
}

// Round 11
// 138.393 us; speedup vs baseline: 1.8481x; 1.8481x over previous
//
#include <hip/hip_runtime.h>

typedef _Float16 hf8  __attribute__((ext_vector_type(8)));
typedef float  f32x16 __attribute__((ext_vector_type(16)));

constexpr int Bn = 512;
constexpr int Nn = 1024;
constexpr int Pn = 2016;
constexpr int H1c = 128;
constexpr int H2c = 64;
constexpr int NCc = 40;
constexpr int NT  = 512;    // threads per block (8 waves)
constexpr int NW  = 8;

// Pre-pack W2 (128x64 f32) + b2 into f16 A-fragments for mfma_f32_32x32x16_f16
// (R8/R10-proven operand geometry), hi-only:
// idx = (((c*2+nt)*2 + kh)*32 + colm)*8 + jj ; c<8: W2[k= c*16+kh*8+jj][j= nt*32+colm]
// c==8: bias chunk — b2[j] in k-slot 0 (kh==0 && jj==0), zeros elsewhere.
__global__ void prep_w2(const float* __restrict__ W2, const float* __restrict__ b2,
                        _Float16* __restrict__ hi) {
    int i = blockIdx.x * 256 + threadIdx.x;
    if (i >= 9216) return;
    int jj = i & 7, colm = (i >> 3) & 31, kh = (i >> 8) & 1, nt = (i >> 9) & 1, c = i >> 10;
    int j = nt * 32 + colm;
    float v;
    if (c < 8) { int k = c * 16 + kh * 8 + jj; v = W2[k * H2c + j]; }
    else       { v = (kh == 0 && jj == 0) ? b2[j] : 0.f; }
    hi[i] = (_Float16)v;    // RNE, rel err <= 2^-11
}

__global__ __launch_bounds__(NT, 4)   // 4 waves/SIMD = 2 blocks/CU, reg budget 128
void mlp_mfma(const float* __restrict__ x, const int* __restrict__ idx,
              const int* __restrict__ perms,
              const float* __restrict__ W1, const float* __restrict__ b1,
              const float* __restrict__ W3, const float* __restrict__ b3,
              const _Float16* __restrict__ w2hi,
              float* __restrict__ out)
{
    // fp16 pair-sum table: entry (gp = g*64 + k1*8+k2, h) at half-index
    //   gp*128 + ((hline ^ (gp&15))<<3) + (h&7),  hline = h>>3  (16B-line XOR swizzle)
    __shared__ _Float16 T2h[256 * 128];   // 64 KiB
    __shared__ float ptsl[24];
    __shared__ float wred[NW][64];
    __shared__ float Hs[64];

    const int t = threadIdx.x, b = blockIdx.x;

    if (t < 24) {
        int k = t / 3, c = t % 3;
        ptsl[t] = x[((size_t)b * Nn + idx[k]) * 3 + c];
    }
    __syncthreads();

    // ---- build T2: 32768 entries, 64 per thread, b1 folded into g==0 ----
    #pragma unroll 1
    for (int i = 0; i < 64; ++i) {
        int e = t + (i << 9);
        int h = e & 127, gp = e >> 7;          // gp in 0..255
        int g = gp >> 6, p = gp & 63, k1 = p >> 3, k2 = p & 7;
        float v = ptsl[k1 * 3 + 0] * W1[(6 * g + 0) * H1c + h]
                + ptsl[k1 * 3 + 1] * W1[(6 * g + 1) * H1c + h]
                + ptsl[k1 * 3 + 2] * W1[(6 * g + 2) * H1c + h]
                + ptsl[k2 * 3 + 0] * W1[(6 * g + 3) * H1c + h]
                + ptsl[k2 * 3 + 1] * W1[(6 * g + 4) * H1c + h]
                + ptsl[k2 * 3 + 2] * W1[(6 * g + 5) * H1c + h];
        if (g == 0) v += b1[h];
        T2h[(gp << 7) + (((h >> 3) ^ (gp & 15)) << 3) + (h & 7)] = (_Float16)v;
    }
    __syncthreads();

    const int lane = t & 63, wave = t >> 6;
    const int kh = lane >> 5, colm = lane & 31;
    const char* Tb = (const char*)T2h;

    float vsum[32];
    #pragma unroll
    for (int q = 0; q < 32; ++q) vsum[q] = 0.f;

    // hoisted per-lane A base and bias fragments (loop-invariant).
    // bias chunk (c==8) starts at element 8*1024 (array is 9*1024 total).
    const _Float16* w2L = w2hi + (kh * 32 + colm) * 8;      // + c*1024 (+512 for nt=1)
    const hf8 bias0 = *(const hf8*)(w2L + 8 * 1024);
    const hf8 bias1 = *(const hf8*)(w2L + 8 * 1024 + 512);
    hf8 Bone = {};
    if (kh == 0) Bone[0] = (_Float16)1.0f;

    // 63 tiles of 32 rows; wave w handles tiles w, w+8, ...
    #pragma unroll 1
    for (int tile = wave; tile < 63; tile += NW) {
        const int4* pp = (const int4*)(perms + ((size_t)b * Pn + (tile << 5) + colm) * 8);
        int4 pa = pp[0];
        int4 pb = pp[1];
        const int gp0 = pa.x * 8 + pa.y;
        const int gp1 = 64  + pa.z * 8 + pa.w;
        const int gp2 = 128 + pb.x * 8 + pb.y;
        const int gp3 = 192 + pb.z * 8 + pb.w;
        // per-row swizzled byte base; per-chunk address = base ^ (c<<5)
        // (bit-exact vs ((2c+kh)^(gp&15))<<4 — HW-verified in R10)
        const int a0 = (gp0 << 8) | ((((kh ^ (gp0 & 1)) | (gp0 & 14))) << 4);
        const int a1 = (gp1 << 8) | ((((kh ^ (gp1 & 1)) | (gp1 & 14))) << 4);
        const int a2 = (gp2 << 8) | ((((kh ^ (gp2 & 1)) | (gp2 & 14))) << 4);
        const int a3 = (gp3 << 8) | ((((kh ^ (gp3 & 1)) | (gp3 & 14))) << 4);

        f32x16 acc0, acc1;
        #pragma unroll
        for (int q = 0; q < 16; ++q) { acc0[q] = 0.f; acc1[q] = 0.f; }

        // depth-2 software pipeline on the A-fragment (global/L1) loads
        hf8 Ah0 = *(const hf8*)(w2L);
        hf8 Ah1 = *(const hf8*)(w2L + 512);

        #pragma unroll 1
        for (int c = 0; c < 8; ++c) {
            // issue next chunk's A loads early (clamped; c==7 reloads chunk 7)
            const int cn = (c < 7 ? c + 1 : 7) * 1024;
            hf8 nAh0 = *(const hf8*)(w2L + cn);
            hf8 nAh1 = *(const hf8*)(w2L + cn + 512);

            const int cx = c << 5;
            hf8 r0 = *(const hf8*)(Tb + (a0 ^ cx));
            hf8 r1 = *(const hf8*)(Tb + (a1 ^ cx));
            hf8 r2 = *(const hf8*)(Tb + (a2 ^ cx));
            hf8 r3 = *(const hf8*)(Tb + (a3 ^ cx));
            hf8 s = (r0 + r1) + (r2 + r3);       // v_pk_add_f16
            hf8 z = {};
            s = __builtin_elementwise_max(s, z); // v_pk_max_f16 (relu) -> exact f16 B

            acc0 = __builtin_amdgcn_mfma_f32_32x32x16_f16(Ah0, s, acc0, 0, 0, 0);
            acc1 = __builtin_amdgcn_mfma_f32_32x32x16_f16(Ah1, s, acc1, 0, 0, 0);

            Ah0 = nAh0;
            Ah1 = nAh1;
        }

        // bias via one-hot MFMA (hoisted fragments)
        acc0 = __builtin_amdgcn_mfma_f32_32x32x16_f16(bias0, Bone, acc0, 0, 0, 0);
        acc1 = __builtin_amdgcn_mfma_f32_32x32x16_f16(bias1, Bone, acc1, 0, 0, 0);

        // relu + accumulate (layer-3 commutes with the mean over rows)
        #pragma unroll
        for (int r = 0; r < 16; ++r) vsum[r]      += fmaxf(acc0[r], 0.f);
        #pragma unroll
        for (int r = 0; r < 16; ++r) vsum[16 + r] += fmaxf(acc1[r], 0.f);
    }

    // ---- reduce over the 32 rows (lanes) per wave ----
    #pragma unroll
    for (int nt = 0; nt < 2; ++nt) {
        #pragma unroll
        for (int r = 0; r < 16; ++r) {
            int j = nt * 32 + (r & 3) + 8 * (r >> 2) + 4 * kh;   // verified C/D row mapping
            float v = vsum[nt * 16 + r];
            v += __shfl_xor(v, 1);
            v += __shfl_xor(v, 2);
            v += __shfl_xor(v, 4);
            v += __shfl_xor(v, 8);
            v += __shfl_xor(v, 16);
            if (colm == 0) wred[wave][j] = v;
        }
    }
    __syncthreads();

    if (t < 64) {
        float s2 = 0.f;
        #pragma unroll
        for (int w = 0; w < NW; ++w) s2 += wred[w][t];
        Hs[t] = s2;
    }
    __syncthreads();

    // ---- layer 3 once per block; block owns batch b -> direct store ----
    if (t < NCc) {
        constexpr float invP = 1.f / (float)Pn;
        float s3 = 0.f;
        #pragma unroll
        for (int j = 0; j < 64; ++j) s3 = fmaf(W3[j * NCc + t], Hs[j], s3);
        out[b * NCc + t] = b3[t] + s3 * invP;
    }
}

extern "C" void kernel_launch(void* const* d_in, const int* in_sizes, int n_in,
                              void* d_out, int out_size, void* d_ws, size_t ws_size,
                              hipStream_t stream) {
    const float* x     = (const float*)d_in[0];
    const int*   idx   = (const int*)  d_in[1];
    const int*   perms = (const int*)  d_in[2];
    const float* W1    = (const float*)d_in[3];
    const float* b1    = (const float*)d_in[4];
    const float* W2    = (const float*)d_in[5];
    const float* b2    = (const float*)d_in[6];
    const float* W3    = (const float*)d_in[7];
    const float* b3    = (const float*)d_in[8];
    float* out = (float*)d_out;

    _Float16* wsHi = (_Float16*)d_ws;

    hipLaunchKernelGGL(prep_w2, dim3(36), dim3(256), 0, stream, W2, b2, wsHi);
    hipLaunchKernelGGL(mlp_mfma, dim3(Bn), dim3(NT), 0, stream,
                       x, idx, perms, W1, b1, W3, b3, wsHi, out);
}

// Round 12
// 136.438 us; speedup vs baseline: 1.8746x; 1.0143x over previous
//
#include <hip/hip_runtime.h>

typedef _Float16 hf8  __attribute__((ext_vector_type(8)));
typedef float  f32x16 __attribute__((ext_vector_type(16)));

constexpr int Bn = 512;
constexpr int Nn = 1024;
constexpr int Pn = 2016;
constexpr int H1c = 128;
constexpr int H2c = 64;
constexpr int NCc = 40;
constexpr int NT  = 512;    // threads per block (8 waves)
constexpr int NW  = 8;
constexpr int TS  = 136;    // T2 row stride in f16 units (272 B: 16B-aligned, quad=(gp+2c+kh)&7 spread)

// Pre-pack W2 (128x64 f32) + b2 into f16 A-fragments for mfma_f32_32x32x16_f16
// (R8/R10/R11-proven operand geometry), hi-only:
// idx = (((c*2+nt)*2 + kh)*32 + colm)*8 + jj ; c<8: W2[k= c*16+kh*8+jj][j= nt*32+colm]
// c==8: bias chunk — b2[j] in k-slot 0 (kh==0 && jj==0), zeros elsewhere.
__global__ void prep_w2(const float* __restrict__ W2, const float* __restrict__ b2,
                        _Float16* __restrict__ hi) {
    int i = blockIdx.x * 256 + threadIdx.x;
    if (i >= 9216) return;
    int jj = i & 7, colm = (i >> 3) & 31, kh = (i >> 8) & 1, nt = (i >> 9) & 1, c = i >> 10;
    int j = nt * 32 + colm;
    float v;
    if (c < 8) { int k = c * 16 + kh * 8 + jj; v = W2[k * H2c + j]; }
    else       { v = (kh == 0 && jj == 0) ? b2[j] : 0.f; }
    hi[i] = (_Float16)v;    // RNE, rel err <= 2^-11
}

__global__ __launch_bounds__(NT, 4)   // 4 waves/SIMD = 2 blocks/CU, reg budget 128
void mlp_mfma(const float* __restrict__ x, const int* __restrict__ idx,
              const int* __restrict__ perms,
              const float* __restrict__ W1, const float* __restrict__ b1,
              const float* __restrict__ W3, const float* __restrict__ b3,
              const _Float16* __restrict__ w2hi,
              float* __restrict__ out)
{
    // fp16 pair-sum table, PADDED LINEAR layout: entry (gp, h) at f16 index gp*136 + h.
    // Row stride 272 B spreads bank-quads by (gp + 2c + kh) & 7 — same conflict
    // structure as the R7-R11 XOR swizzle, but read addr = base + (c*32) immediate.
    __shared__ _Float16 T2h[256 * TS];    // 69632 B
    __shared__ float ptsl[24];
    __shared__ float wred[NW][64];
    __shared__ float Hs[64];

    const int t = threadIdx.x, b = blockIdx.x;

    if (t < 24) {
        int k = t / 3, c = t % 3;
        ptsl[t] = x[((size_t)b * Nn + idx[k]) * 3 + c];
    }
    __syncthreads();

    // ---- build T2: 32768 entries, 64 per thread, b1 folded into g==0 ----
    #pragma unroll 2
    for (int i = 0; i < 64; ++i) {
        int e = t + (i << 9);
        int h = e & 127, gp = e >> 7;          // gp in 0..255
        int g = gp >> 6, p = gp & 63, k1 = p >> 3, k2 = p & 7;
        float v = ptsl[k1 * 3 + 0] * W1[(6 * g + 0) * H1c + h]
                + ptsl[k1 * 3 + 1] * W1[(6 * g + 1) * H1c + h]
                + ptsl[k1 * 3 + 2] * W1[(6 * g + 2) * H1c + h]
                + ptsl[k2 * 3 + 0] * W1[(6 * g + 3) * H1c + h]
                + ptsl[k2 * 3 + 1] * W1[(6 * g + 4) * H1c + h]
                + ptsl[k2 * 3 + 2] * W1[(6 * g + 5) * H1c + h];
        if (g == 0) v += b1[h];
        T2h[gp * TS + h] = (_Float16)v;
    }
    __syncthreads();

    const int lane = t & 63, wave = t >> 6;
    const int kh = lane >> 5, colm = lane & 31;
    const char* Tb = (const char*)T2h;

    float vsum[32];
    #pragma unroll
    for (int q = 0; q < 32; ++q) vsum[q] = 0.f;

    // hoisted per-lane A base and bias fragments (loop-invariant).
    // bias chunk (c==8) starts at element 8*1024 (array is 9*1024 total).
    const _Float16* w2L = w2hi + (kh * 32 + colm) * 8;      // + c*1024 (+512 for nt=1)
    const hf8 bias0 = *(const hf8*)(w2L + 8 * 1024);
    const hf8 bias1 = *(const hf8*)(w2L + 8 * 1024 + 512);
    hf8 Bone = {};
    if (kh == 0) Bone[0] = (_Float16)1.0f;

    // 63 tiles of 32 rows; wave w handles tiles w, w+8, ...
    #pragma unroll 1
    for (int tile = wave; tile < 63; tile += NW) {
        const int4* pp = (const int4*)(perms + ((size_t)b * Pn + (tile << 5) + colm) * 8);
        int4 pa = pp[0];
        int4 pb = pp[1];
        const int gp0 = pa.x * 8 + pa.y;
        const int gp1 = 64  + pa.z * 8 + pa.w;
        const int gp2 = 128 + pb.x * 8 + pb.y;
        const int gp3 = 192 + pb.z * 8 + pb.w;
        // per-row byte base; per-chunk read = base + c*32 (ds imm offset)
        const int khb = kh << 4;
        const int ba0 = gp0 * 272 + khb;
        const int ba1 = gp1 * 272 + khb;
        const int ba2 = gp2 * 272 + khb;
        const int ba3 = gp3 * 272 + khb;

        f32x16 acc0, acc1;
        #pragma unroll
        for (int q = 0; q < 16; ++q) { acc0[q] = 0.f; acc1[q] = 0.f; }

        #pragma unroll 2
        for (int c = 0; c < 8; ++c) {
            const int co = c << 5;
            hf8 r0 = *(const hf8*)(Tb + ba0 + co);
            hf8 r1 = *(const hf8*)(Tb + ba1 + co);
            hf8 r2 = *(const hf8*)(Tb + ba2 + co);
            hf8 r3 = *(const hf8*)(Tb + ba3 + co);
            hf8 s = (r0 + r1) + (r2 + r3);       // v_pk_add_f16
            hf8 z = {};
            s = __builtin_elementwise_max(s, z); // v_pk_max_f16 (relu) -> exact f16 B

            hf8 Ah0 = *(const hf8*)(w2L + c * 1024);
            hf8 Ah1 = *(const hf8*)(w2L + c * 1024 + 512);
            acc0 = __builtin_amdgcn_mfma_f32_32x32x16_f16(Ah0, s, acc0, 0, 0, 0);
            acc1 = __builtin_amdgcn_mfma_f32_32x32x16_f16(Ah1, s, acc1, 0, 0, 0);
        }

        // bias via one-hot MFMA (hoisted fragments)
        acc0 = __builtin_amdgcn_mfma_f32_32x32x16_f16(bias0, Bone, acc0, 0, 0, 0);
        acc1 = __builtin_amdgcn_mfma_f32_32x32x16_f16(bias1, Bone, acc1, 0, 0, 0);

        // relu + accumulate (layer-3 commutes with the mean over rows)
        #pragma unroll
        for (int r = 0; r < 16; ++r) vsum[r]      += fmaxf(acc0[r], 0.f);
        #pragma unroll
        for (int r = 0; r < 16; ++r) vsum[16 + r] += fmaxf(acc1[r], 0.f);
    }

    // ---- reduce over the 32 rows (lanes) per wave ----
    #pragma unroll
    for (int nt = 0; nt < 2; ++nt) {
        #pragma unroll
        for (int r = 0; r < 16; ++r) {
            int j = nt * 32 + (r & 3) + 8 * (r >> 2) + 4 * kh;   // verified C/D row mapping
            float v = vsum[nt * 16 + r];
            v += __shfl_xor(v, 1);
            v += __shfl_xor(v, 2);
            v += __shfl_xor(v, 4);
            v += __shfl_xor(v, 8);
            v += __shfl_xor(v, 16);
            if (colm == 0) wred[wave][j] = v;
        }
    }
    __syncthreads();

    if (t < 64) {
        float s2 = 0.f;
        #pragma unroll
        for (int w = 0; w < NW; ++w) s2 += wred[w][t];
        Hs[t] = s2;
    }
    __syncthreads();

    // ---- layer 3 once per block; block owns batch b -> direct store ----
    if (t < NCc) {
        constexpr float invP = 1.f / (float)Pn;
        float s3 = 0.f;
        #pragma unroll
        for (int j = 0; j < 64; ++j) s3 = fmaf(W3[j * NCc + t], Hs[j], s3);
        out[b * NCc + t] = b3[t] + s3 * invP;
    }
}

extern "C" void kernel_launch(void* const* d_in, const int* in_sizes, int n_in,
                              void* d_out, int out_size, void* d_ws, size_t ws_size,
                              hipStream_t stream) {
    const float* x     = (const float*)d_in[0];
    const int*   idx   = (const int*)  d_in[1];
    const int*   perms = (const int*)  d_in[2];
    const float* W1    = (const float*)d_in[3];
    const float* b1    = (const float*)d_in[4];
    const float* W2    = (const float*)d_in[5];
    const float* b2    = (const float*)d_in[6];
    const float* W3    = (const float*)d_in[7];
    const float* b3    = (const float*)d_in[8];
    float* out = (float*)d_out;

    _Float16* wsHi = (_Float16*)d_ws;

    hipLaunchKernelGGL(prep_w2, dim3(36), dim3(256), 0, stream, W2, b2, wsHi);
    hipLaunchKernelGGL(mlp_mfma, dim3(Bn), dim3(NT), 0, stream,
                       x, idx, perms, W1, b1, W3, b3, wsHi, out);
}